// Round 5
// baseline (1570.449 us; speedup 1.0000x reference)
//
#include <hip/hip_runtime.h>

typedef unsigned short u16;
typedef unsigned int u32;
typedef __attribute__((ext_vector_type(8))) short short8;
typedef __attribute__((ext_vector_type(4))) float f32x4;

constexpr int CB = 64, CT = 512, CX = 8, CH = 128;

__device__ __forceinline__ u16 f2b(float f) {
  u32 u = __float_as_uint(f);
  return (u16)((u + 0x7FFFu + ((u >> 16) & 1u)) >> 16);  // RNE bf16
}
__device__ __forceinline__ u32 pack2bf(float2 v) {
  return (u32)f2b(v.x) | ((u32)f2b(v.y) << 16);
}
__device__ __forceinline__ float sigf(float x) {
  return __fdividef(1.0f, 1.0f + __expf(-x));
}
__device__ __forceinline__ float tanhfast(float x) {
  return 1.0f - __fdividef(2.0f, __expf(2.0f * x) + 1.0f);
}
__device__ __forceinline__ f32x4 mfma16(short8 a, short8 b, f32x4 c) {
  return __builtin_amdgcn_mfma_f32_16x16x32_bf16(a, b, c, 0, 0, 0);
}
// XOR-swizzled LDS tile addressing (R2-verified): 16B-chunk low3 ^= row&7,
// upper chunk bits preserved, low 3 bits of k = offset within chunk.
__device__ __forceinline__ int aswz(int row, int k) {  // K=256 tiles (Asg)
  return row * 256 + ((k & 0xC0) | ((((k >> 3) ^ row) & 7) << 3) | (k & 7));
}
__device__ __forceinline__ int pswz(int row, int k) {  // K=128 tiles (Psg/Gsg)
  return row * 128 + ((k & 0x40) | ((((k >> 3) ^ (row & 7)) & 7) << 3) | (k & 7));
}

// ---------------- ws layout (bytes) ----------------
// 0        : WgwT  bf16 [384][256]  B^T of [w_hh_w; w_ih_w]   (196608 B)
// 196608   : WahcT bf16 [512][128]  B^T of [a_hh | w_hh_c]    (131072 B)
// 327680   : WcaT  bf16 [512][128]  B^T of [w_ih_c | a_ih]    (131072 B)
// 458752   : wica  f32  [B*T][512]  [wi_c_all | a_wi_all]     (67108864 B)

__global__ void prep_kernel(const float* __restrict__ w_ih_c, const float* __restrict__ w_hh_c,
                            const float* __restrict__ a_ih, const float* __restrict__ a_hh,
                            const float* __restrict__ w_ih_w, const float* __restrict__ w_hh_w,
                            u16* __restrict__ WgwT, u16* __restrict__ WahcT, u16* __restrict__ WcaT) {
  int gid = blockIdx.x * blockDim.x + threadIdx.x;  // 224*1024 = 229376
  if (gid < 98304) {                 // WgwT[n][k], n<384, k<256
    int n = gid >> 8, k = gid & 255;
    float v = (k < 128) ? w_hh_w[k * 384 + n] : w_ih_w[(k - 128) * 384 + n];
    WgwT[gid] = f2b(v);
  } else if (gid < 163840) {         // WahcT[n][k], n<512, k<128
    int i = gid - 98304; int n = i >> 7, k = i & 127;
    float v = (n < 128) ? a_hh[k * 128 + n] : w_hh_c[k * 384 + (n - 128)];
    WahcT[i] = f2b(v);
  } else if (gid < 229376) {         // WcaT[n][k], n<512, k<128
    int i = gid - 163840; int n = i >> 7, k = i & 127;
    float v = (n < 384) ? w_ih_c[k * 384 + n] : a_ih[k * 128 + (n - 384)];
    WcaT[i] = f2b(v);
  }
}

// wica[m][n] = sum_k inp[m][k]*Wca[k][n] + bias, m = b*T+t, N=512, K=128
__global__ __launch_bounds__(256) void proj_kernel(const float* __restrict__ inp,
    const u16* __restrict__ WcaT, const float* __restrict__ bias_c,
    const float* __restrict__ a_bias, float* __restrict__ wica) {
  const int m0 = blockIdx.x * 64;
  const int wv = threadIdx.x >> 6, ln = threadIdx.x & 63;
  const int l16 = ln & 15, qd = ln >> 4;
  const int arow = m0 + wv * 16 + l16;
  short8 af[4];
#pragma unroll
  for (int kt = 0; kt < 4; ++kt) {
    const float* p = inp + (size_t)arow * 128 + kt * 32 + qd * 8;
    float4 x0 = *(const float4*)p;
    float4 x1 = *(const float4*)(p + 4);
    short8 a;
    a[0] = (short)f2b(x0.x); a[1] = (short)f2b(x0.y); a[2] = (short)f2b(x0.z); a[3] = (short)f2b(x0.w);
    a[4] = (short)f2b(x1.x); a[5] = (short)f2b(x1.y); a[6] = (short)f2b(x1.z); a[7] = (short)f2b(x1.w);
    af[kt] = a;
  }
  for (int nt = 0; nt < 32; ++nt) {
    const int col = nt * 16 + l16;
    f32x4 acc = {0.f, 0.f, 0.f, 0.f};
#pragma unroll
    for (int kt = 0; kt < 4; ++kt) {
      short8 bf = *(const short8*)(WcaT + (size_t)col * 128 + kt * 32 + qd * 8);
      acc = mfma16(af[kt], bf, acc);
    }
    const float bias = (col < 384) ? bias_c[col] : a_bias[col - 384];
#pragma unroll
    for (int r = 0; r < 4; ++r) {
      const int orow = m0 + wv * 16 + qd * 4 + r;
      wica[(size_t)orow * 512 + col] = acc[r] + bias;
    }
  }
}

// 1 batch per block, 64 blocks. A rows 0-7 = slots, rows 8-15 = zero pad.
// LDS is padded past 80 KB ON PURPOSE: the AMDGPU backend derives its VGPR
// budget from LDS-limited occupancy (R3: 57.8KB -> 2 WG/CU -> 4 waves/SIMD
// -> 128 VGPRs -> weight frags rematerialized from L2 every step). >80KB
// forces 1 WG/CU -> 2 waves/SIMD -> 256-VGPR budget so the 160 weight regs
// stay resident. Runtime is unchanged: 64 blocks already get 1 CU each.
__global__ __launch_bounds__(512) void scan_kernel(
    const float* __restrict__ skip_words,  // [B][T][X][128]
    const int* __restrict__ srcp,          // [B][T][X]
    const int* __restrict__ cntp,          // [B][T]
    const float* __restrict__ bias_w,      // [384]
    const u16* __restrict__ WgwT,          // [384][256]
    const u16* __restrict__ WahcT,         // [512][128]
    const float* __restrict__ wica,        // [B*T][512]
    float* __restrict__ out)               // hs [B][T][128] ; cs follows
{
  const int b = blockIdx.x;
  const int tid = threadIdx.x;
  const int wv = tid >> 6, ln = tid & 63, l16 = ln & 15, qd = ln >> 4;
  const int h = wv * 16 + l16;

  float* hs = out + (size_t)b * CT * CH;
  float* cs = out + (size_t)(CB + b) * CT * CH;
  const float* swb = skip_words + (size_t)b * CT * CX * CH;
  const int* srb = srcp + b * CT * CX;
  const int* cnb = cntp + b * CT;
  const float* wicab = wica + (size_t)b * CT * 512;

  __shared__ __align__(16) u16 Asg[16 * 256];    // gw A: [h_x | sw]
  __shared__ __align__(16) u16 Psg[16 * 128];    // alpha A: c1_skip (rows 8-15 zero)
  __shared__ __align__(16) u16 Gsg[16 * 128];    // gc A: row 0 = h0 (rows 1-15 zero)
  __shared__ __align__(16) float Csg[16 * 132];  // gathered c_x (fp32)
  __shared__ __align__(16) u32 pad_occ[15360];   // 61.4KB occupancy pad (see above)
  if ((int)blockIdx.x < 0) pad_occ[tid] = tid;   // unprovable guard: keeps alloc

  // zero A/P/G fully (pad rows must stay zero; staged rows overwritten below)
  for (int i = tid; i < 2048; i += 512) ((u32*)Asg)[i] = 0;
  for (int i = tid; i < 1024; i += 512) ((u32*)Psg)[i] = 0;
  for (int i = tid; i < 1024; i += 512) ((u32*)Gsg)[i] = 0;

  // persistent B-fragments (registers) --------------------------------------
  short8 wgwf[3][8];   // gw gates f,i,g: col g*128+h, K=256
#pragma unroll
  for (int g = 0; g < 3; ++g) {
    const int n = g * 128 + h;
#pragma unroll
    for (int kt = 0; kt < 8; ++kt)
      wgwf[g][kt] = *(const short8*)(WgwT + (size_t)n * 256 + kt * 32 + qd * 8);
  }
  short8 waca[4];      // alpha: a_hh col h, K=128
#pragma unroll
  for (int kt = 0; kt < 4; ++kt)
    waca[kt] = *(const short8*)(WahcT + (size_t)h * 128 + kt * 32 + qd * 8);
  short8 wacc[3][4];   // gc gates i,o,g: w_hh_c col g*128+h, K=128
#pragma unroll
  for (int g = 0; g < 3; ++g) {
    const int n = 128 + g * 128 + h;
#pragma unroll
    for (int kt = 0; kt < 4; ++kt)
      wacc[g][kt] = *(const short8*)(WahcT + (size_t)n * 128 + kt * 32 + qd * 8);
  }
  const float bw0 = bias_w[h], bw1 = bias_w[128 + h], bw2 = bias_w[256 + h];

  __syncthreads();  // zeros visible before staging overwrites rows 0-7

  // preamble: stage step 0 (gathers hit poison at t=0; masked by cnt(0)=0)
  {
    const int s0 = srb[wv];
    float2 hA = *(const float2*)(hs + (size_t)s0 * CH + 2 * ln);
    float2 cA = *(const float2*)(cs + (size_t)s0 * CH + 2 * ln);
    float2 wA = *(const float2*)(swb + (size_t)wv * CH + 2 * ln);
    *(u32*)&Asg[aswz(wv, 2 * ln)] = pack2bf(hA);
    *(u32*)&Asg[aswz(wv, 128 + 2 * ln)] = pack2bf(wA);
    *(float2*)&Csg[wv * 132 + 2 * ln] = cA;
  }
  int srcF = srb[CX + wv];  // src(t+1) for slot wv
  __syncthreads();

  for (int t = 0; t < CT; ++t) {
    // ---- phase1: issue ALL global loads; consumed at phase4/phase5 --------
    const int cntc = cnb[t];
    const float wi0 = wicab[(size_t)t * 512 + h];
    const float wi1 = wicab[(size_t)t * 512 + 128 + h];
    const float wi2 = wicab[(size_t)t * 512 + 256 + h];
    const float wi3 = wicab[(size_t)t * 512 + 384 + h];
    const bool st = (t + 1 < CT);
    bool fr = false;
    float2 hA = {0.f, 0.f}, cA = {0.f, 0.f}, wA = {0.f, 0.f};
    int fm = 0, srcFn = 0;
    if (st) {
      fr = (srcF == t);  // wave-uniform
      if (!fr) {         // row <= t-1: stored >=1 step ago, drained by barrier 2
        hA = *(const float2*)(hs + (size_t)srcF * CH + 2 * ln);
        cA = *(const float2*)(cs + (size_t)srcF * CH + 2 * ln);
      }
      wA = *(const float2*)(swb + ((size_t)(t + 1) * CX + wv) * CH + 2 * ln);
      int4 a0 = *(const int4*)(srb + (t + 1) * CX);
      int4 a1 = *(const int4*)(srb + (t + 1) * CX + 4);
      fm = (a0.x == t) | ((a0.y == t) << 1) | ((a0.z == t) << 2) | ((a0.w == t) << 3) |
           ((a1.x == t) << 4) | ((a1.y == t) << 5) | ((a1.z == t) << 6) | ((a1.w == t) << 7);
      if (t + 2 < CT) srcFn = srb[(t + 2) * CX + wv];
    }

    // ---- phase2: gw = [h_x|sw]@[w_hh_w;w_ih_w] ; gc = h0@w_hh_c -----------
    f32x4 d0 = {0.f, 0.f, 0.f, 0.f}, d1 = d0, d2 = d0;
    f32x4 e1 = d0, e2 = d0, e3 = d0;
#pragma unroll
    for (int kt = 0; kt < 8; ++kt) {
      short8 a = *(const short8*)&Asg[aswz(l16, kt * 32 + qd * 8)];
      d0 = mfma16(a, wgwf[0][kt], d0);
      d1 = mfma16(a, wgwf[1][kt], d1);
      d2 = mfma16(a, wgwf[2][kt], d2);
    }
#pragma unroll
    for (int kt = 0; kt < 4; ++kt) {
      short8 g = *(const short8*)&Gsg[pswz(l16, kt * 32 + qd * 8)];
      e1 = mfma16(g, wacc[0][kt], e1);
      e2 = mfma16(g, wacc[1][kt], e2);
      e3 = mfma16(g, wacc[2][kt], e3);
    }
    float c1s[4] = {0.f, 0.f, 0.f, 0.f};
    if (qd < 2) {  // rows 0..7 = real slots
#pragma unroll
      for (int r = 0; r < 4; ++r) {
        const int row = qd * 4 + r;
        const float cx = Csg[row * 132 + h];
        const float v = sigf(d0[r] + bw0) * cx + sigf(d1[r] + bw1) * tanhfast(d2[r] + bw2);
        c1s[r] = v;
        Psg[pswz(row, h)] = f2b(v);
      }
    }
    // barrier 1: publish Psg (LDS only) — global prefetch stays in flight
    asm volatile("s_waitcnt lgkmcnt(0)\n\ts_barrier" ::: "memory");

    // ---- phase3: alpha = c1_skip @ a_hh (B resident in regs) --------------
    f32x4 e0 = {0.f, 0.f, 0.f, 0.f};
#pragma unroll
    for (int kt = 0; kt < 4; ++kt) {
      short8 p = *(const short8*)&Psg[pswz(l16, kt * 32 + qd * 8)];
      e0 = mfma16(p, waca[kt], e0);
    }

    // ---- phase4: softmax-merge --------------------------------------------
    const float gi = __shfl(e1[0], l16, 64);  // gc D row 0 lives in lanes 0-15, reg 0
    const float go = __shfl(e2[0], l16, 64);
    const float gg = __shfl(e3[0], l16, 64);
    const float i_g = sigf(gi + wi0);
    const float o_g = sigf(go + wi1);
    const float g_g = tanhfast(gg + wi2);
    float pe = 0.f, pec = 0.f;
#pragma unroll
    for (int r = 0; r < 4; ++r) {
      const int row = qd * 4 + r;
      if (row < cntc) {  // qd>=2 rows always masked (cnt<=8)
        const float e = __expf(sigf(e0[r] + wi3));
        pe += e;
        pec += e * c1s[r];
      }
    }
    pe += __shfl_xor(pe, 16, 64);  pec += __shfl_xor(pec, 16, 64);
    pe += __shfl_xor(pe, 32, 64);  pec += __shfl_xor(pec, 32, 64);
    const float ei = __expf(i_g);
    const float c1 = __fdividef(ei * g_g + pec, ei + pe);
    const float h1 = o_g * tanhfast(c1);

    // ---- phase5: outputs + stage A(t+1) (prefetch has ~full-step cover) ---
    if (qd == 0) {  // one writer per h
      hs[(size_t)t * CH + h] = h1;
      cs[(size_t)t * CH + h] = c1;
      Gsg[pswz(0, h)] = f2b(h1);  // h0 for step t+1
      if (fm) {                   // fresh rows: forward h1/c1 straight to LDS
        const u16 hb = f2b(h1);
#pragma unroll
        for (int s = 0; s < 8; ++s)
          if ((fm >> s) & 1) {
            Asg[aswz(s, h)] = hb;
            Csg[s * 132 + h] = c1;
          }
      }
    }
    if (st) {
      if (!fr) {
        *(u32*)&Asg[aswz(wv, 2 * ln)] = pack2bf(hA);
        *(float2*)&Csg[wv * 132 + 2 * ln] = cA;
      }
      *(u32*)&Asg[aswz(wv, 128 + 2 * ln)] = pack2bf(wA);
    }
    __syncthreads();  // barrier 2: publish staging + drain hs/cs stores
    srcF = srcFn;
  }
}

extern "C" void kernel_launch(void* const* d_in, const int* in_sizes, int n_in,
                              void* d_out, int out_size, void* d_ws, size_t ws_size,
                              hipStream_t stream) {
  (void)in_sizes; (void)n_in; (void)out_size; (void)ws_size;
  const float* inp    = (const float*)d_in[0];
  const float* skw    = (const float*)d_in[1];
  const int*   ssrc   = (const int*)d_in[3];
  const int*   scnt   = (const int*)d_in[4];
  const float* w_ih_c = (const float*)d_in[5];
  const float* w_hh_c = (const float*)d_in[6];
  const float* bias_c = (const float*)d_in[7];
  const float* a_ih   = (const float*)d_in[8];
  const float* a_hh   = (const float*)d_in[9];
  const float* a_bias = (const float*)d_in[10];
  const float* w_ih_w = (const float*)d_in[11];
  const float* w_hh_w = (const float*)d_in[12];
  const float* bias_w = (const float*)d_in[13];

  char* ws = (char*)d_ws;
  u16*   WgwT  = (u16*)(ws);
  u16*   WahcT = (u16*)(ws + 196608);
  u16*   WcaT  = (u16*)(ws + 327680);
  float* wica  = (float*)(ws + 458752);
  float* out   = (float*)d_out;

  prep_kernel<<<224, 1024, 0, stream>>>(w_ih_c, w_hh_c, a_ih, a_hh, w_ih_w, w_hh_w,
                                        WgwT, WahcT, WcaT);
  proj_kernel<<<512, 256, 0, stream>>>(inp, WcaT, bias_c, a_bias, wica);
  scan_kernel<<<64, 512, 0, stream>>>(skw, ssrc, scnt, bias_w, WgwT, WahcT, wica, out);
}

// Round 6
// 1532.156 us; speedup vs baseline: 1.0250x; 1.0250x over previous
//
#include <hip/hip_runtime.h>

typedef unsigned short u16;
typedef unsigned int u32;
typedef __attribute__((ext_vector_type(8))) short short8;
typedef __attribute__((ext_vector_type(4))) float f32x4;

constexpr int CB = 64, CT = 512, CX = 8, CH = 128;

__device__ __forceinline__ u16 f2b(float f) {
  u32 u = __float_as_uint(f);
  return (u16)((u + 0x7FFFu + ((u >> 16) & 1u)) >> 16);  // RNE bf16
}
__device__ __forceinline__ u32 pack2bf(float2 v) {
  return (u32)f2b(v.x) | ((u32)f2b(v.y) << 16);
}
__device__ __forceinline__ float sigf(float x) {
  return __fdividef(1.0f, 1.0f + __expf(-x));
}
__device__ __forceinline__ float tanhfast(float x) {
  return 1.0f - __fdividef(2.0f, __expf(2.0f * x) + 1.0f);
}
__device__ __forceinline__ f32x4 mfma16(short8 a, short8 b, f32x4 c) {
  return __builtin_amdgcn_mfma_f32_16x16x32_bf16(a, b, c, 0, 0, 0);
}
// Swizzles redesigned (R5) so hot-loop addresses fold to base+imm:
//  chunk c=k>>3; offset-in-row = (c>>3)*64 + ((c&7)^perm(row))*8 + (k&7)
//  Asg: perm=row&7 ; Psg/Gsg: perm=(row>>1)&7 (row-pairs share -> write bases fold)
__device__ __forceinline__ int aswz2(int row, int k) {
  int c = k >> 3;
  return row * 256 + ((c >> 3) * 64) + (((c & 7) ^ (row & 7)) * 8) + (k & 7);
}
__device__ __forceinline__ int pswz2(int row, int k) {
  int c = k >> 3;
  return row * 128 + ((c >> 3) * 64) + (((c & 7) ^ ((row >> 1) & 7)) * 8) + (k & 7);
}

// ---------------- ws layout (bytes) ----------------
// 0        : WgwT  bf16 [384][256]  B^T of [w_hh_w; w_ih_w]   (196608 B)
// 196608   : WahcT bf16 [512][128]  B^T of [a_hh | w_hh_c]    (131072 B)
// 327680   : WcaT  bf16 [512][128]  B^T of [w_ih_c | a_ih]    (131072 B)
// 458752   : wica  f32  [B*T][512]  [wi_c_all | a_wi_all]     (67108864 B)

__global__ void prep_kernel(const float* __restrict__ w_ih_c, const float* __restrict__ w_hh_c,
                            const float* __restrict__ a_ih, const float* __restrict__ a_hh,
                            const float* __restrict__ w_ih_w, const float* __restrict__ w_hh_w,
                            u16* __restrict__ WgwT, u16* __restrict__ WahcT, u16* __restrict__ WcaT) {
  int gid = blockIdx.x * blockDim.x + threadIdx.x;  // 224*1024 = 229376
  if (gid < 98304) {                 // WgwT[n][k], n<384, k<256
    int n = gid >> 8, k = gid & 255;
    float v = (k < 128) ? w_hh_w[k * 384 + n] : w_ih_w[(k - 128) * 384 + n];
    WgwT[gid] = f2b(v);
  } else if (gid < 163840) {         // WahcT[n][k], n<512, k<128
    int i = gid - 98304; int n = i >> 7, k = i & 127;
    float v = (n < 128) ? a_hh[k * 128 + n] : w_hh_c[k * 384 + (n - 128)];
    WahcT[i] = f2b(v);
  } else if (gid < 229376) {         // WcaT[n][k], n<512, k<128
    int i = gid - 163840; int n = i >> 7, k = i & 127;
    float v = (n < 384) ? w_ih_c[k * 384 + n] : a_ih[k * 128 + (n - 384)];
    WcaT[i] = f2b(v);
  }
}

// wica[m][n] = sum_k inp[m][k]*Wca[k][n] + bias, m = b*T+t, N=512, K=128
__global__ __launch_bounds__(256) void proj_kernel(const float* __restrict__ inp,
    const u16* __restrict__ WcaT, const float* __restrict__ bias_c,
    const float* __restrict__ a_bias, float* __restrict__ wica) {
  const int m0 = blockIdx.x * 64;
  const int wv = threadIdx.x >> 6, ln = threadIdx.x & 63;
  const int l16 = ln & 15, qd = ln >> 4;
  const int arow = m0 + wv * 16 + l16;
  short8 af[4];
#pragma unroll
  for (int kt = 0; kt < 4; ++kt) {
    const float* p = inp + (size_t)arow * 128 + kt * 32 + qd * 8;
    float4 x0 = *(const float4*)p;
    float4 x1 = *(const float4*)(p + 4);
    short8 a;
    a[0] = (short)f2b(x0.x); a[1] = (short)f2b(x0.y); a[2] = (short)f2b(x0.z); a[3] = (short)f2b(x0.w);
    a[4] = (short)f2b(x1.x); a[5] = (short)f2b(x1.y); a[6] = (short)f2b(x1.z); a[7] = (short)f2b(x1.w);
    af[kt] = a;
  }
  for (int nt = 0; nt < 32; ++nt) {
    const int col = nt * 16 + l16;
    f32x4 acc = {0.f, 0.f, 0.f, 0.f};
#pragma unroll
    for (int kt = 0; kt < 4; ++kt) {
      short8 bf = *(const short8*)(WcaT + (size_t)col * 128 + kt * 32 + qd * 8);
      acc = mfma16(af[kt], bf, acc);
    }
    const float bias = (col < 384) ? bias_c[col] : a_bias[col - 384];
#pragma unroll
    for (int r = 0; r < 4; ++r) {
      const int orow = m0 + wv * 16 + qd * 4 + r;
      wica[(size_t)orow * 512 + col] = acc[r] + bias;
    }
  }
}

// 1 batch per block, 64 blocks (1 WG/CU at runtime). No __launch_bounds__:
// it overrides amdgpu_waves_per_eu (R3's mistake). waves_per_eu(1,2) raises
// the compiler's register budget to >=256 so the ~160 persistent weight regs
// stay resident instead of being rematerialized from L2 every step.
__global__ __attribute__((amdgpu_flat_work_group_size(512, 512), amdgpu_waves_per_eu(1, 2)))
void scan_kernel(
    const float* __restrict__ skip_words,  // [B][T][X][128]
    const int* __restrict__ srcp,          // [B][T][X]
    const int* __restrict__ cntp,          // [B][T]
    const float* __restrict__ bias_w,      // [384]
    const u16* __restrict__ WgwT,          // [384][256]
    const u16* __restrict__ WahcT,         // [512][128]
    const float* __restrict__ wica,        // [B*T][512]
    float* __restrict__ out)               // hs [B][T][128] ; cs follows
{
  const int b = blockIdx.x;
  const int tid = threadIdx.x;
  const int wv = tid >> 6, ln = tid & 63, l16 = ln & 15, qd = ln >> 4;
  const int h = wv * 16 + l16;

  float* hs = out + (size_t)b * CT * CH;
  float* cs = out + (size_t)(CB + b) * CT * CH;
  const float* swb = skip_words + (size_t)b * CT * CX * CH;
  const int* srb = srcp + b * CT * CX;
  const int* cnb = cntp + b * CT;
  const float* wicab = wica + (size_t)b * CT * 512;

  __shared__ __align__(16) u16 Asg[16 * 256];    // gw A: [h_x | sw]
  __shared__ __align__(16) u16 Psg[16 * 128];    // alpha A: c1_skip (rows 8-15 zero)
  __shared__ __align__(16) u16 Gsg[16 * 128];    // gc A: row 0 = h0 (rows 1-15 zero)
  __shared__ __align__(16) float Csg[16 * 132];  // gathered c_x (fp32)

  // zero fully (pad rows must stay zero; staged rows overwritten below)
  for (int i = tid; i < 2048; i += 512) ((u32*)Asg)[i] = 0;
  for (int i = tid; i < 1024; i += 512) ((u32*)Psg)[i] = 0;
  for (int i = tid; i < 1024; i += 512) ((u32*)Gsg)[i] = 0;

  // ---- loop-invariant LDS base pointers (all hot accesses = base + imm) ----
  // Asg reads: k = kt*32+qd*8 -> even kt chunk = qd^..., odd kt chunk = (qd|4)^...
  const u16* aRe = Asg + l16 * 256 + ((qd ^ (l16 & 7)) * 8);
  const u16* aRo = Asg + l16 * 256 + (((qd | 4) ^ (l16 & 7)) * 8);
  const u16* pRe = Psg + l16 * 128 + ((qd ^ ((l16 >> 1) & 7)) * 8);
  const u16* pRo = Psg + l16 * 128 + (((qd | 4) ^ ((l16 >> 1) & 7)) * 8);
  const u16* gRe = Gsg + l16 * 128 + ((qd ^ ((l16 >> 1) & 7)) * 8);
  const u16* gRo = Gsg + l16 * 128 + (((qd | 4) ^ ((l16 >> 1) & 7)) * 8);
  // Asg staging write (row=wv, k=2ln): lane-constant; sw-part = +128 u16
  u16* aW = Asg + wv * 256 + (ln >> 5) * 64 + ((((ln >> 2) & 7) ^ (wv & 7)) * 8) + ((2 * ln) & 7);
  // Psg epilogue writes: rows qd*4+{0,1} at pW01+{0,128}; +{2,3} at pW23+{0,128}
  u16* pW01 = Psg + (qd * 4) * 128 + (h >> 6) * 64 + ((((h >> 3) & 7) ^ (2 * qd)) * 8) + (h & 7);
  u16* pW23 = Psg + (qd * 4 + 2) * 128 + (h >> 6) * 64 + ((((h >> 3) & 7) ^ (2 * qd + 1)) * 8) + (h & 7);
  // Gsg row-0 write (perm(0)=0): lane-constant
  u16* gW = Gsg + (h >> 6) * 64 + (((h >> 3) & 7) * 8) + (h & 7);
  // Csg: reads cR[r*132], staging write cW
  const float* cR = Csg + (qd * 4) * 132 + h;
  float* cW = Csg + wv * 132 + 2 * ln;

  // persistent B-fragments (registers) --------------------------------------
  short8 wgwf[3][8];   // gw gates f,i,g: col g*128+h, K=256
#pragma unroll
  for (int g = 0; g < 3; ++g) {
    const int n = g * 128 + h;
#pragma unroll
    for (int kt = 0; kt < 8; ++kt)
      wgwf[g][kt] = *(const short8*)(WgwT + (size_t)n * 256 + kt * 32 + qd * 8);
  }
  short8 waca[4];      // alpha: a_hh col h, K=128
#pragma unroll
  for (int kt = 0; kt < 4; ++kt)
    waca[kt] = *(const short8*)(WahcT + (size_t)h * 128 + kt * 32 + qd * 8);
  short8 wacc[3][4];   // gc gates i,o,g: w_hh_c col g*128+h, K=128
#pragma unroll
  for (int g = 0; g < 3; ++g) {
    const int n = 128 + g * 128 + h;
#pragma unroll
    for (int kt = 0; kt < 4; ++kt)
      wacc[g][kt] = *(const short8*)(WahcT + (size_t)n * 128 + kt * 32 + qd * 8);
  }
  const float bw0 = bias_w[h], bw1 = bias_w[128 + h], bw2 = bias_w[256 + h];

  __syncthreads();  // zeros visible before staging overwrites rows 0-7

  // preamble: stage step 0 (gathers hit poison at t=0; masked by cnt(0)=0)
  {
    const int s0 = srb[wv];
    float2 hA = *(const float2*)(hs + (size_t)s0 * CH + 2 * ln);
    float2 cA = *(const float2*)(cs + (size_t)s0 * CH + 2 * ln);
    float2 wA = *(const float2*)(swb + (size_t)wv * CH + 2 * ln);
    *(u32*)aW = pack2bf(hA);
    *(u32*)(aW + 128) = pack2bf(wA);
    *(float2*)cW = cA;
  }
  int srcF = srb[CX + wv];  // src(t+1) for slot wv
  __syncthreads();

  for (int t = 0; t < CT; ++t) {
    // ---- phase1: issue ALL global loads; consumed at phase4/phase5 --------
    const int cntc = cnb[t];
    const float* wp = wicab + (size_t)t * 512 + h;
    const float wi0 = wp[0], wi1 = wp[128], wi2 = wp[256], wi3 = wp[384];
    const bool st = (t + 1 < CT);
    bool fr = false;
    float2 hA = {0.f, 0.f}, cA = {0.f, 0.f}, wA = {0.f, 0.f};
    int fm = 0, srcFn = 0;
    if (st) {
      fr = (srcF == t);  // wave-uniform
      if (!fr) {         // row <= t-1: stored >=1 step ago, drained by barrier 2
        hA = *(const float2*)(hs + (size_t)srcF * CH + 2 * ln);
        cA = *(const float2*)(cs + (size_t)srcF * CH + 2 * ln);
      }
      wA = *(const float2*)(swb + ((size_t)(t + 1) * CX + wv) * CH + 2 * ln);
      int4 a0 = *(const int4*)(srb + (t + 1) * CX);
      int4 a1 = *(const int4*)(srb + (t + 1) * CX + 4);
      fm = (a0.x == t) | ((a0.y == t) << 1) | ((a0.z == t) << 2) | ((a0.w == t) << 3) |
           ((a1.x == t) << 4) | ((a1.y == t) << 5) | ((a1.z == t) << 6) | ((a1.w == t) << 7);
      if (t + 2 < CT) srcFn = srb[(t + 2) * CX + wv];
    }

    // ---- phase2: gw = [h_x|sw]@[w_hh_w;w_ih_w] ; gc = h0@w_hh_c -----------
    f32x4 d0 = {0.f, 0.f, 0.f, 0.f}, d1 = d0, d2 = d0;
    f32x4 e1 = d0, e2 = d0, e3 = d0;
#pragma unroll
    for (int kt = 0; kt < 8; ++kt) {
      short8 a = *(const short8*)((kt & 1 ? aRo : aRe) + (kt >> 1) * 64);
      d0 = mfma16(a, wgwf[0][kt], d0);
      d1 = mfma16(a, wgwf[1][kt], d1);
      d2 = mfma16(a, wgwf[2][kt], d2);
    }
#pragma unroll
    for (int kt = 0; kt < 4; ++kt) {
      short8 g = *(const short8*)((kt & 1 ? gRo : gRe) + (kt >> 1) * 64);
      e1 = mfma16(g, wacc[0][kt], e1);
      e2 = mfma16(g, wacc[1][kt], e2);
      e3 = mfma16(g, wacc[2][kt], e3);
    }
    float c1s[4] = {0.f, 0.f, 0.f, 0.f};
    if (qd < 2) {  // rows 0..7 = real slots
#pragma unroll
      for (int r = 0; r < 4; ++r) {
        const float cx = cR[r * 132];
        const float v = sigf(d0[r] + bw0) * cx + sigf(d1[r] + bw1) * tanhfast(d2[r] + bw2);
        c1s[r] = v;
        u16* pw = (r < 2 ? pW01 : pW23);
        pw[(r & 1) * 128] = f2b(v);
      }
    }
    // barrier 1: publish Psg (LDS only) — global prefetch stays in flight
    asm volatile("s_waitcnt lgkmcnt(0)\n\ts_barrier" ::: "memory");

    // ---- phase3: alpha = c1_skip @ a_hh (B resident in regs) --------------
    f32x4 e0 = {0.f, 0.f, 0.f, 0.f};
#pragma unroll
    for (int kt = 0; kt < 4; ++kt) {
      short8 p = *(const short8*)((kt & 1 ? pRo : pRe) + (kt >> 1) * 64);
      e0 = mfma16(p, waca[kt], e0);
    }

    // ---- phase4: softmax-merge --------------------------------------------
    const float gi = __shfl(e1[0], l16, 64);  // gc D row 0 lives in lanes 0-15, reg 0
    const float go = __shfl(e2[0], l16, 64);
    const float gg = __shfl(e3[0], l16, 64);
    const float i_g = sigf(gi + wi0);
    const float o_g = sigf(go + wi1);
    const float g_g = tanhfast(gg + wi2);
    float pe = 0.f, pec = 0.f;
#pragma unroll
    for (int r = 0; r < 4; ++r) {
      const int row = qd * 4 + r;
      const float e = __expf(sigf(e0[r] + wi3));
      const bool ok = (row < cntc);  // qd>=2 rows always masked (cnt<=8)
      pe += ok ? e : 0.f;
      pec += ok ? e * c1s[r] : 0.f;
    }
    pe += __shfl_xor(pe, 16, 64);  pec += __shfl_xor(pec, 16, 64);
    pe += __shfl_xor(pe, 32, 64);  pec += __shfl_xor(pec, 32, 64);
    const float ei = __expf(i_g);
    const float c1 = __fdividef(ei * g_g + pec, ei + pe);
    const float h1 = o_g * tanhfast(c1);

    // ---- phase5: outputs + stage A(t+1) (prefetch has ~full-step cover) ---
    if (qd == 0) {  // one writer per h
      hs[(size_t)t * CH + h] = h1;
      cs[(size_t)t * CH + h] = c1;
      *gW = f2b(h1);  // h0 for step t+1
      if (fm) {       // fresh rows: forward h1/c1 straight to LDS (rare-ish)
        const u16 hb = f2b(h1);
#pragma unroll
        for (int s = 0; s < 8; ++s)
          if ((fm >> s) & 1) {
            Asg[aswz2(s, h)] = hb;
            Csg[s * 132 + h] = c1;
          }
      }
    }
    if (st) {
      if (!fr) {
        *(u32*)aW = pack2bf(hA);
        *(float2*)cW = cA;
      }
      *(u32*)(aW + 128) = pack2bf(wA);
    }
    __syncthreads();  // barrier 2: publish staging + drain hs/cs stores
    srcF = srcFn;
  }
}

extern "C" void kernel_launch(void* const* d_in, const int* in_sizes, int n_in,
                              void* d_out, int out_size, void* d_ws, size_t ws_size,
                              hipStream_t stream) {
  (void)in_sizes; (void)n_in; (void)out_size; (void)ws_size;
  const float* inp    = (const float*)d_in[0];
  const float* skw    = (const float*)d_in[1];
  const int*   ssrc   = (const int*)d_in[3];
  const int*   scnt   = (const int*)d_in[4];
  const float* w_ih_c = (const float*)d_in[5];
  const float* w_hh_c = (const float*)d_in[6];
  const float* bias_c = (const float*)d_in[7];
  const float* a_ih   = (const float*)d_in[8];
  const float* a_hh   = (const float*)d_in[9];
  const float* a_bias = (const float*)d_in[10];
  const float* w_ih_w = (const float*)d_in[11];
  const float* w_hh_w = (const float*)d_in[12];
  const float* bias_w = (const float*)d_in[13];

  char* ws = (char*)d_ws;
  u16*   WgwT  = (u16*)(ws);
  u16*   WahcT = (u16*)(ws + 196608);
  u16*   WcaT  = (u16*)(ws + 327680);
  float* wica  = (float*)(ws + 458752);
  float* out   = (float*)d_out;

  prep_kernel<<<224, 1024, 0, stream>>>(w_ih_c, w_hh_c, a_ih, a_hh, w_ih_w, w_hh_w,
                                        WgwT, WahcT, WcaT);
  proj_kernel<<<512, 256, 0, stream>>>(inp, WcaT, bias_c, a_bias, wica);
  scan_kernel<<<64, 512, 0, stream>>>(skw, ssrc, scnt, bias_w, WgwT, WahcT, wica, out);
}